// Round 9
// baseline (191.374 us; speedup 1.0000x reference)
//
#include <hip/hip_runtime.h>
#include <hip/hip_fp16.h>

#define ALPHA 0.3f
#define B_SZ 4096
#define D_SZ 1024
#define CT_STRIDE 132   // multiple of 4: aligned half4 stores, 2-way banks on scans
#define BIGF 3.0e38f
#define SENT_F 60000.0f // fp16-representable sentinel >> any d2 (~4100 max)

typedef __attribute__((ext_vector_type(8))) _Float16 half8;
typedef __attribute__((ext_vector_type(4))) _Float16 half4;
typedef __attribute__((ext_vector_type(2))) _Float16 half2v;
typedef __attribute__((ext_vector_type(4))) float floatx4;

typedef __attribute__((address_space(1))) const void* gas_t;
typedef __attribute__((address_space(3))) void* las_t;

__device__ __forceinline__ float wave_reduce_add(float v) {
#pragma unroll
    for (int off = 32; off; off >>= 1) v += __shfl_xor(v, off);
    return v;
}

// sorted ascending insert of x into best[0..9] (branchless, scalar f32)
__device__ __forceinline__ void insert10(float (&best)[10], float x) {
#pragma unroll
    for (int p = 0; p < 10; ++p) {
        float lo = fminf(best[p], x);
        x = fmaxf(best[p], x);
        best[p] = lo;
    }
}

// packed: two independent sorted-10 lists; lowers to v_pk_min/max_f16
__device__ __forceinline__ void insert10p(half2v (&b)[10], half2v x) {
#pragma unroll
    for (int p = 0; p < 10; ++p) {
        half2v lo = __builtin_elementwise_min(b[p], x);
        x = __builtin_elementwise_max(b[p], x);
        b[p] = lo;
    }
}

// ---------------------------------------------------------------------------
// prep: fp32 -> fp16 convert, row norms x2/y2, exact threshold m[i], and
// zero-init of d_out (harness poisons it; merge accumulates atomically).
// ---------------------------------------------------------------------------
__global__ void __launch_bounds__(256) prep_kernel(
    const float* __restrict__ in1, const float* __restrict__ in2,
    _Float16* __restrict__ Xh, _Float16* __restrict__ Yh,
    float* __restrict__ x2, float* __restrict__ y2, float* __restrict__ mth,
    float* __restrict__ out) {
    int row = blockIdx.x;
    int t = threadIdx.x;
    if (row == 0 && t < 4) out[t] = 0.0f;
    const float4* a4 = (const float4*)(in1 + (size_t)row * D_SZ);
    const float4* b4 = (const float4*)(in2 + (size_t)row * D_SZ);
    float4 a = a4[t], b = b4[t];
    half4 ha = {(_Float16)a.x, (_Float16)a.y, (_Float16)a.z, (_Float16)a.w};
    half4 hb = {(_Float16)b.x, (_Float16)b.y, (_Float16)b.z, (_Float16)b.w};
    ((half4*)(Xh + (size_t)row * D_SZ))[t] = ha;
    ((half4*)(Yh + (size_t)row * D_SZ))[t] = hb;
    float sa = a.x * a.x + a.y * a.y + a.z * a.z + a.w * a.w;
    float sb = b.x * b.x + b.y * b.y + b.z * b.z + b.w * b.w;
    float d0 = a.x - b.x, d1 = a.y - b.y, d2v = a.z - b.z, d3 = a.w - b.w;
    float sd = d0 * d0 + d1 * d1 + d2v * d2v + d3 * d3;
    sa = wave_reduce_add(sa);
    sb = wave_reduce_add(sb);
    sd = wave_reduce_add(sd);
    __shared__ float red[3][4];
    int wave = t >> 6, lane = t & 63;
    if (lane == 0) { red[0][wave] = sa; red[1][wave] = sb; red[2][wave] = sd; }
    __syncthreads();
    if (t == 0) {
        x2[row] = red[0][0] + red[0][1] + red[0][2] + red[0][3];
        y2[row] = red[1][0] + red[1][1] + red[1][2] + red[1][3];
        mth[row] = sqrtf(red[2][0] + red[2][1] + red[2][2] + red[2][3]) + ALPHA;
    }
}

// ---------------------------------------------------------------------------
// gemm_topk: G = Xh @ Yh^T tile (128x128), BK=32 K-loop (proven spill-free,
// conflict-free). Fused epilogue: d2 tile -> LDS fp16 col-major
// (Ct[col*132+row], half4 writes), diag pre-clear, packed fp16 selection:
//   waves 0,1: IRR — lane scans a row-PAIR (packed halves = two rows),
//              col-halves merged in-wave via shfl_xor(32).
//   waves 2,3: RII — lane owns a full column (packed halves = even/odd row
//              streams), merged via 16-bit-rotate + 10 packed inserts.
// Candidates: 10 fp16 per (row, tile), layout [row][tile][10].
// ---------------------------------------------------------------------------
__global__ void __launch_bounds__(256, 4) gemm_topk_kernel(
    const _Float16* __restrict__ Xh, const _Float16* __restrict__ Yh,
    const float* __restrict__ x2, const float* __restrict__ y2,
    _Float16* __restrict__ CandI, _Float16* __restrict__ CandR) {
    __shared__ _Float16 smem[16896];   // 33792 B: As+Bs (8192 h) | Ct (16896 h)
    _Float16* As = smem;               // 128 x 32 halves
    _Float16* Bs = smem + 4096;
    int tid = threadIdx.x;
    int wave = tid >> 6, lane = tid & 63;
    int waveR = wave >> 1, waveC = wave & 1;
    int bx = blockIdx.x, by = blockIdx.y;
    int q = lane >> 4, mrow = lane & 15;

    floatx4 acc[4][4] = {};

    // Per-thread staging source (swizzled k-slice), invariant over k0.
    int c0 = tid, c1 = 256 + tid;
    int r0 = c0 >> 2, q0 = (c0 & 3) ^ ((r0 >> 1) & 3);
    int r1 = c1 >> 2, q1 = (c1 & 3) ^ ((r1 >> 1) & 3);
    const _Float16* gA0 = Xh + (size_t)(by * 128 + r0) * D_SZ + q0 * 8;
    const _Float16* gB0 = Yh + (size_t)(bx * 128 + r0) * D_SZ + q0 * 8;
    const _Float16* gA1 = Xh + (size_t)(by * 128 + r1) * D_SZ + q1 * 8;
    const _Float16* gB1 = Yh + (size_t)(bx * 128 + r1) * D_SZ + q1 * 8;
    _Float16* la0 = &As[(wave * 64) * 8];
    _Float16* lb0 = &Bs[(wave * 64) * 8];
    _Float16* la1 = &As[(256 + wave * 64) * 8];
    _Float16* lb1 = &Bs[(256 + wave * 64) * 8];

    int aoff[4], boff[4];
#pragma unroll
    for (int mi = 0; mi < 4; ++mi) {
        int R = waveR * 64 + mi * 16 + mrow;
        aoff[mi] = R * 32 + (q ^ ((R >> 1) & 3)) * 8;
    }
#pragma unroll
    for (int ni = 0; ni < 4; ++ni) {
        int R = waveC * 64 + ni * 16 + mrow;
        boff[ni] = R * 32 + (q ^ ((R >> 1) & 3)) * 8;
    }

    for (int k0 = 0; k0 < D_SZ; k0 += 32) {
        __syncthreads();
        __builtin_amdgcn_global_load_lds((gas_t)(const void*)(gA0 + k0), (las_t)(void*)la0, 16, 0, 0);
        __builtin_amdgcn_global_load_lds((gas_t)(const void*)(gB0 + k0), (las_t)(void*)lb0, 16, 0, 0);
        __builtin_amdgcn_global_load_lds((gas_t)(const void*)(gA1 + k0), (las_t)(void*)la1, 16, 0, 0);
        __builtin_amdgcn_global_load_lds((gas_t)(const void*)(gB1 + k0), (las_t)(void*)lb1, 16, 0, 0);
        __syncthreads();
        half8 af[4], bf[4];
#pragma unroll
        for (int mi = 0; mi < 4; ++mi) af[mi] = *(const half8*)&As[aoff[mi]];
#pragma unroll
        for (int ni = 0; ni < 4; ++ni) bf[ni] = *(const half8*)&Bs[boff[ni]];
#pragma unroll
        for (int mi = 0; mi < 4; ++mi)
#pragma unroll
            for (int ni = 0; ni < 4; ++ni)
                acc[mi][ni] = __builtin_amdgcn_mfma_f32_16x16x32_f16(af[mi], bf[ni], acc[mi][ni], 0, 0, 0);
    }
    __syncthreads();  // staging LDS dead; Ct takes over

    // Phase 1: d2 tile -> LDS fp16 col-major: Ct[col*132 + row].
    // C/D layout: col = lane&15, row = q*4 + reg -> 4 consecutive rows = half4.
    _Float16* Ct = smem;
#pragma unroll
    for (int ni = 0; ni < 4; ++ni) {
        int lc = waveC * 64 + ni * 16 + mrow;
        float y2v = y2[bx * 128 + lc];
#pragma unroll
        for (int mi = 0; mi < 4; ++mi) {
            int lr0 = waveR * 64 + mi * 16 + q * 4;
            int gr0 = by * 128 + lr0;
            floatx4 v = acc[mi][ni];
            half4 hv = {(_Float16)(x2[gr0 + 0] + y2v - 2.0f * v[0]),
                        (_Float16)(x2[gr0 + 1] + y2v - 2.0f * v[1]),
                        (_Float16)(x2[gr0 + 2] + y2v - 2.0f * v[2]),
                        (_Float16)(x2[gr0 + 3] + y2v - 2.0f * v[3])};
            *(half4*)&Ct[lc * CT_STRIDE + lr0] = hv;
        }
    }
    __syncthreads();
    // Diagonal pre-clear (removes all per-element diag masking below).
    if (bx == by && tid < 128) Ct[tid * CT_STRIDE + tid] = (_Float16)SENT_F;
    __syncthreads();

    const half2v sent2 = {(_Float16)SENT_F, (_Float16)SENT_F};

    if (wave < 2) {
        // IRR: lane -> row-pair p (rows 2p, 2p+1), col-half chalf.
        int p = wave * 32 + (lane & 31);     // 0..63
        int chalf = lane >> 5;
        half2v b[10];
#pragma unroll
        for (int i = 0; i < 10; ++i) b[i] = sent2;
#pragma unroll 8
        for (int i = 0; i < 64; ++i) {
            int c = chalf * 64 + i;
            half2v v = *(const half2v*)&Ct[c * CT_STRIDE + 2 * p];
            insert10p(b, v);
        }
        // merge the two col-halves (lanes l <-> l^32)
        half2v t[10];
#pragma unroll
        for (int k = 0; k < 10; ++k)
            t[k] = __builtin_bit_cast(half2v, __shfl_xor(__builtin_bit_cast(int, b[k]), 32));
#pragma unroll
        for (int k = 0; k < 10; ++k) insert10p(b, t[k]);
        if (lane < 32) {
            int grow = by * 128 + 2 * p;
            unsigned int* d0 = (unsigned int*)CandI + ((size_t)grow * 32 + bx) * 5;
            unsigned int* d1 = d0 + 32 * 5;  // row grow+1
#pragma unroll
            for (int k = 0; k < 5; ++k) {
                unsigned int u0 = __builtin_bit_cast(unsigned int, b[2 * k]);
                unsigned int u1 = __builtin_bit_cast(unsigned int, b[2 * k + 1]);
                d0[k] = (u0 & 0xFFFFu) | (u1 << 16);            // low halves = row 2p
                d1[k] = (u0 >> 16) | (u1 & 0xFFFF0000u);        // high halves = row 2p+1
            }
        }
    } else {
        // RII: lane -> full column c; packed halves = even/odd row sub-streams.
        int c = (wave - 2) * 64 + lane;      // 0..127
        half2v b[10];
#pragma unroll
        for (int i = 0; i < 10; ++i) b[i] = sent2;
        const half2v* colp = (const half2v*)&Ct[c * CT_STRIDE];
#pragma unroll 8
        for (int i = 0; i < 64; ++i) insert10p(b, colp[i]);
        // merge even/odd streams: insert the 16-bit-rotated lists (snapshot first)
        half2v sw[10];
#pragma unroll
        for (int k = 0; k < 10; ++k) {
            unsigned int u = __builtin_bit_cast(unsigned int, b[k]);
            sw[k] = __builtin_bit_cast(half2v, (u >> 16) | (u << 16));
        }
#pragma unroll
        for (int k = 0; k < 10; ++k) insert10p(b, sw[k]);
        // low halves of b[0..9] = column top-10
        int gcol = bx * 128 + c;
        unsigned int* d = (unsigned int*)CandR + ((size_t)gcol * 32 + by) * 5;
#pragma unroll
        for (int k = 0; k < 5; ++k) {
            unsigned int u0 = __builtin_bit_cast(unsigned int, b[2 * k]);
            unsigned int u1 = __builtin_bit_cast(unsigned int, b[2 * k + 1]);
            d[k] = (u0 & 0xFFFFu) | (u1 << 16);
        }
    }
}

// ---------------------------------------------------------------------------
// merge: 2048 blocks, ONE row per wave (max TLP — the 10-round reduce is a
// serial latency chain, so parallelism, not per-wave batching, wins; R8's
// 4-rows-per-wave variant cost ~13 us). Rows [0,4096) = IRR, [4096,8192) =
// RII; each block's 4 rows are side-uniform. Block-level LDS reduce then 2
// pre-scaled atomicAdds into d_out (no finalize kernel).
// ---------------------------------------------------------------------------
__global__ void __launch_bounds__(256) merge_kernel(
    const _Float16* __restrict__ CandI, const _Float16* __restrict__ CandR,
    const float* __restrict__ mth, float* __restrict__ out) {
    int wave = threadIdx.x >> 6, lane = threadIdx.x & 63;
    int r = blockIdx.x * 4 + wave;              // 0..8191
    int side = blockIdx.x >> 10;                // 0 = IRR, 1 = RII (block-uniform)
    int row = r & (B_SZ - 1);
    const _Float16* cp = (side ? CandR : CandI) + (size_t)row * 320;
    float best[10];
#pragma unroll
    for (int i = 0; i < 10; ++i) best[i] = BIGF;
#pragma unroll
    for (int j = 0; j < 5; ++j) insert10(best, (float)cp[j * 64 + lane]);

    float mrow = mth[row];
    float s = 0.f, z = 0.f;
#pragma unroll
    for (int round = 0; round < 10; ++round) {
        float v0 = best[0];
        float g = v0;
#pragma unroll
        for (int off = 32; off; off >>= 1) g = fminf(g, __shfl_xor(g, off));
        unsigned long long ball = __ballot(v0 == g);
        int leader = __ffsll(ball) - 1;
        if (lane == leader) {
#pragma unroll
            for (int p = 0; p < 9; ++p) best[p] = best[p + 1];
            best[9] = BIGF;
        }
        float d = sqrtf(fmaxf(g, 0.f));
        float c = fmaxf(mrow - d, 0.f);
        s += c;
        z += (c == 0.f) ? 1.f : 0.f;
    }
    __shared__ float red[2][4];
    if (lane == 0) { red[0][wave] = s; red[1][wave] = z; }
    __syncthreads();
    if (threadIdx.x == 0) {
        const float inv = 1.0f / (float)(B_SZ * 10);
        float ss = (red[0][0] + red[0][1] + red[0][2] + red[0][3]) * inv;
        float zz = (red[1][0] + red[1][1] + red[1][2] + red[1][3]) * inv;
        atomicAdd(&out[side], ss);      // out[0]=loss_irr, out[1]=loss_rii
        atomicAdd(&out[2 + side], zz);  // out[2]=bad_irr,  out[3]=bad_rii
    }
}

// ---------------------------------------------------------------------------
extern "C" void kernel_launch(void* const* d_in, const int* in_sizes, int n_in,
                              void* d_out, int out_size, void* d_ws, size_t ws_size,
                              hipStream_t stream) {
    const float* in1 = (const float*)d_in[0];
    const float* in2 = (const float*)d_in[1];
    float* out = (float*)d_out;

    char* ws = (char*)d_ws;
    const size_t MB = 1024 * 1024;
    _Float16* Xh = (_Float16*)(ws);                  // 8 MiB
    _Float16* Yh = (_Float16*)(ws + 8 * MB);         // 8 MiB
    _Float16* CandI = (_Float16*)(ws + 16 * MB);     // 4096*32*10*2B = 2.62 MB
    _Float16* CandR = (_Float16*)(ws + 19 * MB);     // 2.62 MB
    float* x2   = (float*)(ws + 22 * MB);
    float* y2   = x2 + B_SZ;
    float* mth  = y2 + B_SZ;
    const size_t needed = 22 * MB + (size_t)(3 * B_SZ) * sizeof(float);
    if (ws_size < needed) return;

    hipLaunchKernelGGL(prep_kernel, dim3(B_SZ), dim3(256), 0, stream,
                       in1, in2, Xh, Yh, x2, y2, mth, out);
    hipLaunchKernelGGL(gemm_topk_kernel, dim3(32, 32), dim3(256), 0, stream,
                       Xh, Yh, x2, y2, CandI, CandR);
    hipLaunchKernelGGL(merge_kernel, dim3(2048), dim3(256), 0, stream,
                       CandI, CandR, mth, out);
}

// Round 10
// 145.451 us; speedup vs baseline: 1.3157x; 1.3157x over previous
//
#include <hip/hip_runtime.h>
#include <hip/hip_fp16.h>

#define ALPHA 0.3f
#define B_SZ 4096
#define D_SZ 1024
#define CT_STRIDE 132   // multiple of 4: aligned half4 stores, 2-way banks on scans
#define BIGF 3.0e38f
#define SENT_F 60000.0f // fp16-representable sentinel >> any d2 (~4100 max)

typedef __attribute__((ext_vector_type(8))) _Float16 half8;
typedef __attribute__((ext_vector_type(4))) _Float16 half4;
typedef __attribute__((ext_vector_type(2))) _Float16 half2v;
typedef __attribute__((ext_vector_type(4))) float floatx4;

typedef __attribute__((address_space(1))) const void* gas_t;
typedef __attribute__((address_space(3))) void* las_t;

__device__ __forceinline__ float wave_reduce_add(float v) {
#pragma unroll
    for (int off = 32; off; off >>= 1) v += __shfl_xor(v, off);
    return v;
}

// sorted ascending insert of x into best[0..9] (branchless, scalar f32)
__device__ __forceinline__ void insert10(float (&best)[10], float x) {
#pragma unroll
    for (int p = 0; p < 10; ++p) {
        float lo = fminf(best[p], x);
        x = fmaxf(best[p], x);
        best[p] = lo;
    }
}

// packed: two independent sorted-10 lists; lowers to v_pk_min/max_f16
__device__ __forceinline__ void insert10p(half2v (&b)[10], half2v x) {
#pragma unroll
    for (int p = 0; p < 10; ++p) {
        half2v lo = __builtin_elementwise_min(b[p], x);
        x = __builtin_elementwise_max(b[p], x);
        b[p] = lo;
    }
}

// ---------------------------------------------------------------------------
// prep: fp32 -> fp16 convert, row norms x2/y2, exact threshold m[i].
// ---------------------------------------------------------------------------
__global__ void __launch_bounds__(256) prep_kernel(
    const float* __restrict__ in1, const float* __restrict__ in2,
    _Float16* __restrict__ Xh, _Float16* __restrict__ Yh,
    float* __restrict__ x2, float* __restrict__ y2, float* __restrict__ mth) {
    int row = blockIdx.x;
    int t = threadIdx.x;
    const float4* a4 = (const float4*)(in1 + (size_t)row * D_SZ);
    const float4* b4 = (const float4*)(in2 + (size_t)row * D_SZ);
    float4 a = a4[t], b = b4[t];
    half4 ha = {(_Float16)a.x, (_Float16)a.y, (_Float16)a.z, (_Float16)a.w};
    half4 hb = {(_Float16)b.x, (_Float16)b.y, (_Float16)b.z, (_Float16)b.w};
    ((half4*)(Xh + (size_t)row * D_SZ))[t] = ha;
    ((half4*)(Yh + (size_t)row * D_SZ))[t] = hb;
    float sa = a.x * a.x + a.y * a.y + a.z * a.z + a.w * a.w;
    float sb = b.x * b.x + b.y * b.y + b.z * b.z + b.w * b.w;
    float d0 = a.x - b.x, d1 = a.y - b.y, d2v = a.z - b.z, d3 = a.w - b.w;
    float sd = d0 * d0 + d1 * d1 + d2v * d2v + d3 * d3;
    sa = wave_reduce_add(sa);
    sb = wave_reduce_add(sb);
    sd = wave_reduce_add(sd);
    __shared__ float red[3][4];
    int wave = t >> 6, lane = t & 63;
    if (lane == 0) { red[0][wave] = sa; red[1][wave] = sb; red[2][wave] = sd; }
    __syncthreads();
    if (t == 0) {
        x2[row] = red[0][0] + red[0][1] + red[0][2] + red[0][3];
        y2[row] = red[1][0] + red[1][1] + red[1][2] + red[1][3];
        mth[row] = sqrtf(red[2][0] + red[2][1] + red[2][2] + red[2][3]) + ALPHA;
    }
}

// ---------------------------------------------------------------------------
// gemm_topk: G = Xh @ Yh^T tile (128x128), BK=32 K-loop (proven spill-free,
// conflict-free). Fused epilogue: d2 tile -> LDS fp16 col-major
// (Ct[col*132+row], half4 writes), diag pre-clear, packed fp16 selection:
//   waves 0,1: IRR — lane scans a row-PAIR (packed halves = two rows),
//              col-halves merged in-wave via shfl_xor(32).
//   waves 2,3: RII — lane owns a full column (packed halves = even/odd row
//              streams), merged via 16-bit-rotate + 10 packed inserts.
// Candidates: 10 fp16 per (row, tile), layout [row][tile][10].
// ---------------------------------------------------------------------------
__global__ void __launch_bounds__(256, 4) gemm_topk_kernel(
    const _Float16* __restrict__ Xh, const _Float16* __restrict__ Yh,
    const float* __restrict__ x2, const float* __restrict__ y2,
    _Float16* __restrict__ CandI, _Float16* __restrict__ CandR) {
    __shared__ _Float16 smem[16896];   // 33792 B: As+Bs (8192 h) | Ct (16896 h)
    _Float16* As = smem;               // 128 x 32 halves
    _Float16* Bs = smem + 4096;
    int tid = threadIdx.x;
    int wave = tid >> 6, lane = tid & 63;
    int waveR = wave >> 1, waveC = wave & 1;
    int bx = blockIdx.x, by = blockIdx.y;
    int q = lane >> 4, mrow = lane & 15;

    floatx4 acc[4][4] = {};

    // Per-thread staging source (swizzled k-slice), invariant over k0.
    int c0 = tid, c1 = 256 + tid;
    int r0 = c0 >> 2, q0 = (c0 & 3) ^ ((r0 >> 1) & 3);
    int r1 = c1 >> 2, q1 = (c1 & 3) ^ ((r1 >> 1) & 3);
    const _Float16* gA0 = Xh + (size_t)(by * 128 + r0) * D_SZ + q0 * 8;
    const _Float16* gB0 = Yh + (size_t)(bx * 128 + r0) * D_SZ + q0 * 8;
    const _Float16* gA1 = Xh + (size_t)(by * 128 + r1) * D_SZ + q1 * 8;
    const _Float16* gB1 = Yh + (size_t)(bx * 128 + r1) * D_SZ + q1 * 8;
    _Float16* la0 = &As[(wave * 64) * 8];
    _Float16* lb0 = &Bs[(wave * 64) * 8];
    _Float16* la1 = &As[(256 + wave * 64) * 8];
    _Float16* lb1 = &Bs[(256 + wave * 64) * 8];

    int aoff[4], boff[4];
#pragma unroll
    for (int mi = 0; mi < 4; ++mi) {
        int R = waveR * 64 + mi * 16 + mrow;
        aoff[mi] = R * 32 + (q ^ ((R >> 1) & 3)) * 8;
    }
#pragma unroll
    for (int ni = 0; ni < 4; ++ni) {
        int R = waveC * 64 + ni * 16 + mrow;
        boff[ni] = R * 32 + (q ^ ((R >> 1) & 3)) * 8;
    }

    for (int k0 = 0; k0 < D_SZ; k0 += 32) {
        __syncthreads();
        __builtin_amdgcn_global_load_lds((gas_t)(const void*)(gA0 + k0), (las_t)(void*)la0, 16, 0, 0);
        __builtin_amdgcn_global_load_lds((gas_t)(const void*)(gB0 + k0), (las_t)(void*)lb0, 16, 0, 0);
        __builtin_amdgcn_global_load_lds((gas_t)(const void*)(gA1 + k0), (las_t)(void*)la1, 16, 0, 0);
        __builtin_amdgcn_global_load_lds((gas_t)(const void*)(gB1 + k0), (las_t)(void*)lb1, 16, 0, 0);
        __syncthreads();
        half8 af[4], bf[4];
#pragma unroll
        for (int mi = 0; mi < 4; ++mi) af[mi] = *(const half8*)&As[aoff[mi]];
#pragma unroll
        for (int ni = 0; ni < 4; ++ni) bf[ni] = *(const half8*)&Bs[boff[ni]];
#pragma unroll
        for (int mi = 0; mi < 4; ++mi)
#pragma unroll
            for (int ni = 0; ni < 4; ++ni)
                acc[mi][ni] = __builtin_amdgcn_mfma_f32_16x16x32_f16(af[mi], bf[ni], acc[mi][ni], 0, 0, 0);
    }
    __syncthreads();  // staging LDS dead; Ct takes over

    // Phase 1: d2 tile -> LDS fp16 col-major: Ct[col*132 + row].
    // C/D layout: col = lane&15, row = q*4 + reg -> 4 consecutive rows = half4.
    _Float16* Ct = smem;
#pragma unroll
    for (int ni = 0; ni < 4; ++ni) {
        int lc = waveC * 64 + ni * 16 + mrow;
        float y2v = y2[bx * 128 + lc];
#pragma unroll
        for (int mi = 0; mi < 4; ++mi) {
            int lr0 = waveR * 64 + mi * 16 + q * 4;
            int gr0 = by * 128 + lr0;
            floatx4 v = acc[mi][ni];
            half4 hv = {(_Float16)(x2[gr0 + 0] + y2v - 2.0f * v[0]),
                        (_Float16)(x2[gr0 + 1] + y2v - 2.0f * v[1]),
                        (_Float16)(x2[gr0 + 2] + y2v - 2.0f * v[2]),
                        (_Float16)(x2[gr0 + 3] + y2v - 2.0f * v[3])};
            *(half4*)&Ct[lc * CT_STRIDE + lr0] = hv;
        }
    }
    __syncthreads();
    // Diagonal pre-clear (removes all per-element diag masking below).
    if (bx == by && tid < 128) Ct[tid * CT_STRIDE + tid] = (_Float16)SENT_F;
    __syncthreads();

    const half2v sent2 = {(_Float16)SENT_F, (_Float16)SENT_F};

    if (wave < 2) {
        // IRR: lane -> row-pair p (rows 2p, 2p+1), col-half chalf.
        int p = wave * 32 + (lane & 31);     // 0..63
        int chalf = lane >> 5;
        half2v b[10];
#pragma unroll
        for (int i = 0; i < 10; ++i) b[i] = sent2;
#pragma unroll 8
        for (int i = 0; i < 64; ++i) {
            int c = chalf * 64 + i;
            half2v v = *(const half2v*)&Ct[c * CT_STRIDE + 2 * p];
            insert10p(b, v);
        }
        // merge the two col-halves (lanes l <-> l^32)
        half2v t[10];
#pragma unroll
        for (int k = 0; k < 10; ++k)
            t[k] = __builtin_bit_cast(half2v, __shfl_xor(__builtin_bit_cast(int, b[k]), 32));
#pragma unroll
        for (int k = 0; k < 10; ++k) insert10p(b, t[k]);
        if (lane < 32) {
            int grow = by * 128 + 2 * p;
            unsigned int* d0 = (unsigned int*)CandI + ((size_t)grow * 32 + bx) * 5;
            unsigned int* d1 = d0 + 32 * 5;  // row grow+1
#pragma unroll
            for (int k = 0; k < 5; ++k) {
                unsigned int u0 = __builtin_bit_cast(unsigned int, b[2 * k]);
                unsigned int u1 = __builtin_bit_cast(unsigned int, b[2 * k + 1]);
                d0[k] = (u0 & 0xFFFFu) | (u1 << 16);            // low halves = row 2p
                d1[k] = (u0 >> 16) | (u1 & 0xFFFF0000u);        // high halves = row 2p+1
            }
        }
    } else {
        // RII: lane -> full column c; packed halves = even/odd row sub-streams.
        int c = (wave - 2) * 64 + lane;      // 0..127
        half2v b[10];
#pragma unroll
        for (int i = 0; i < 10; ++i) b[i] = sent2;
        const half2v* colp = (const half2v*)&Ct[c * CT_STRIDE];
#pragma unroll 8
        for (int i = 0; i < 64; ++i) insert10p(b, colp[i]);
        // merge even/odd streams: insert the 16-bit-rotated lists (snapshot first)
        half2v sw[10];
#pragma unroll
        for (int k = 0; k < 10; ++k) {
            unsigned int u = __builtin_bit_cast(unsigned int, b[k]);
            sw[k] = __builtin_bit_cast(half2v, (u >> 16) | (u << 16));
        }
#pragma unroll
        for (int k = 0; k < 10; ++k) insert10p(b, sw[k]);
        // low halves of b[0..9] = column top-10
        int gcol = bx * 128 + c;
        unsigned int* d = (unsigned int*)CandR + ((size_t)gcol * 32 + by) * 5;
#pragma unroll
        for (int k = 0; k < 5; ++k) {
            unsigned int u0 = __builtin_bit_cast(unsigned int, b[2 * k]);
            unsigned int u1 = __builtin_bit_cast(unsigned int, b[2 * k + 1]);
            d[k] = (u0 & 0xFFFFu) | (u1 << 16);
        }
    }
}

// ---------------------------------------------------------------------------
// merge: 2048 blocks, ONE row per wave (max TLP; the 10-round reduce is a
// serial latency chain). NO atomics — per-row partials to Srow/Zrow (R9's
// 4096 same-address atomicAdds serialized at ~33 cyc each = 57.9 us).
// ---------------------------------------------------------------------------
__global__ void __launch_bounds__(256) merge_kernel(
    const _Float16* __restrict__ CandI, const _Float16* __restrict__ CandR,
    const float* __restrict__ mth,
    float* __restrict__ Srow, float* __restrict__ Zrow) {
    int wave = threadIdx.x >> 6, lane = threadIdx.x & 63;
    int r = blockIdx.x * 4 + wave;              // 0..8191
    int row = r & (B_SZ - 1);
    const _Float16* cp = ((r < B_SZ) ? CandI : CandR) + (size_t)row * 320;
    float best[10];
#pragma unroll
    for (int i = 0; i < 10; ++i) best[i] = BIGF;
#pragma unroll
    for (int j = 0; j < 5; ++j) insert10(best, (float)cp[j * 64 + lane]);

    float mrow = mth[row];
    float s = 0.f, z = 0.f;
#pragma unroll
    for (int round = 0; round < 10; ++round) {
        float v0 = best[0];
        float g = v0;
#pragma unroll
        for (int off = 32; off; off >>= 1) g = fminf(g, __shfl_xor(g, off));
        unsigned long long ball = __ballot(v0 == g);
        int leader = __ffsll(ball) - 1;
        if (lane == leader) {
#pragma unroll
            for (int p = 0; p < 9; ++p) best[p] = best[p + 1];
            best[9] = BIGF;
        }
        float d = sqrtf(fmaxf(g, 0.f));
        float c = fmaxf(mrow - d, 0.f);
        s += c;
        z += (c == 0.f) ? 1.f : 0.f;
    }
    if (lane == 0) { Srow[r] = s; Zrow[r] = z; }
}

// ---------------------------------------------------------------------------
// finalize: reduce per-row partials -> [loss_irr, loss_rii, bad_irr, bad_rii]
// Srow/Zrow are 8192 floats each = 2048 float4: [0,1024) IRR, [1024,2048) RII.
// ---------------------------------------------------------------------------
__global__ void __launch_bounds__(256) finalize_kernel(
    const float* __restrict__ Srow, const float* __restrict__ Zrow,
    float* __restrict__ out) {
    __shared__ float red[256][4];
    int t = threadIdx.x;
    float s0 = 0, s1 = 0, z0 = 0, z1 = 0;
#pragma unroll
    for (int k = 0; k < 8; ++k) {
        int i = k * 256 + t;
        float4 sv = ((const float4*)Srow)[i];
        float4 zv = ((const float4*)Zrow)[i];
        float ss = sv.x + sv.y + sv.z + sv.w;
        float zz = zv.x + zv.y + zv.z + zv.w;
        if (i < 1024) { s0 += ss; z0 += zz; } else { s1 += ss; z1 += zz; }
    }
    red[t][0] = s0; red[t][1] = s1; red[t][2] = z0; red[t][3] = z1;
    __syncthreads();
    for (int off = 128; off > 0; off >>= 1) {
        if (t < off) {
#pragma unroll
            for (int j = 0; j < 4; ++j) red[t][j] += red[t + off][j];
        }
        __syncthreads();
    }
    if (t == 0) {
        const float inv = 1.0f / (float)(B_SZ * 10);
        out[0] = red[0][0] * inv;  // loss_irr
        out[1] = red[0][1] * inv;  // loss_rii
        out[2] = red[0][2] * inv;  // bad_irr
        out[3] = red[0][3] * inv;  // bad_rii
    }
}

// ---------------------------------------------------------------------------
extern "C" void kernel_launch(void* const* d_in, const int* in_sizes, int n_in,
                              void* d_out, int out_size, void* d_ws, size_t ws_size,
                              hipStream_t stream) {
    const float* in1 = (const float*)d_in[0];
    const float* in2 = (const float*)d_in[1];
    float* out = (float*)d_out;

    char* ws = (char*)d_ws;
    const size_t MB = 1024 * 1024;
    _Float16* Xh = (_Float16*)(ws);                  // 8 MiB
    _Float16* Yh = (_Float16*)(ws + 8 * MB);         // 8 MiB
    _Float16* CandI = (_Float16*)(ws + 16 * MB);     // 4096*32*10*2B = 2.62 MB
    _Float16* CandR = (_Float16*)(ws + 19 * MB);     // 2.62 MB
    float* x2   = (float*)(ws + 22 * MB);
    float* y2   = x2 + B_SZ;
    float* mth  = y2 + B_SZ;
    float* Srow = mth + B_SZ;                        // 8192 floats
    float* Zrow = Srow + 2 * B_SZ;                   // 8192 floats
    const size_t needed = 22 * MB + (size_t)(3 * B_SZ + 4 * B_SZ) * sizeof(float);
    if (ws_size < needed) return;

    hipLaunchKernelGGL(prep_kernel, dim3(B_SZ), dim3(256), 0, stream,
                       in1, in2, Xh, Yh, x2, y2, mth);
    hipLaunchKernelGGL(gemm_topk_kernel, dim3(32, 32), dim3(256), 0, stream,
                       Xh, Yh, x2, y2, CandI, CandR);
    hipLaunchKernelGGL(merge_kernel, dim3(2048), dim3(256), 0, stream,
                       CandI, CandR, mth, Srow, Zrow);
    hipLaunchKernelGGL(finalize_kernel, dim3(1), dim3(256), 0, stream,
                       Srow, Zrow, out);
}

// Round 11
// 144.301 us; speedup vs baseline: 1.3262x; 1.0080x over previous
//
#include <hip/hip_runtime.h>
#include <hip/hip_fp16.h>

#define ALPHA 0.3f
#define B_SZ 4096
#define D_SZ 1024
#define CT_STRIDE 132   // multiple of 4: aligned half4 stores, 2-way banks on scans
#define BIGF 3.0e38f
#define SENT_F 60000.0f // fp16-representable sentinel >> any d2 (~4100 max)

typedef __attribute__((ext_vector_type(8))) _Float16 half8;
typedef __attribute__((ext_vector_type(4))) _Float16 half4;
typedef __attribute__((ext_vector_type(2))) _Float16 half2v;
typedef __attribute__((ext_vector_type(4))) float floatx4;

typedef __attribute__((address_space(1))) const void* gas_t;
typedef __attribute__((address_space(3))) void* las_t;

__device__ __forceinline__ float wave_reduce_add(float v) {
#pragma unroll
    for (int off = 32; off; off >>= 1) v += __shfl_xor(v, off);
    return v;
}

// sorted ascending insert of x into best[0..9] (branchless, scalar f32)
__device__ __forceinline__ void insert10(float (&best)[10], float x) {
#pragma unroll
    for (int p = 0; p < 10; ++p) {
        float lo = fminf(best[p], x);
        x = fmaxf(best[p], x);
        best[p] = lo;
    }
}

// packed: two independent sorted-10 lists; lowers to v_pk_min/max_f16
__device__ __forceinline__ void insert10p(half2v (&b)[10], half2v x) {
#pragma unroll
    for (int p = 0; p < 10; ++p) {
        half2v lo = __builtin_elementwise_min(b[p], x);
        x = __builtin_elementwise_max(b[p], x);
        b[p] = lo;
    }
}

// ---------------------------------------------------------------------------
// prep: fp32 -> fp16 convert, row norms x2/y2, exact threshold m[i].
// ---------------------------------------------------------------------------
__global__ void __launch_bounds__(256) prep_kernel(
    const float* __restrict__ in1, const float* __restrict__ in2,
    _Float16* __restrict__ Xh, _Float16* __restrict__ Yh,
    float* __restrict__ x2, float* __restrict__ y2, float* __restrict__ mth) {
    int row = blockIdx.x;
    int t = threadIdx.x;
    const float4* a4 = (const float4*)(in1 + (size_t)row * D_SZ);
    const float4* b4 = (const float4*)(in2 + (size_t)row * D_SZ);
    float4 a = a4[t], b = b4[t];
    half4 ha = {(_Float16)a.x, (_Float16)a.y, (_Float16)a.z, (_Float16)a.w};
    half4 hb = {(_Float16)b.x, (_Float16)b.y, (_Float16)b.z, (_Float16)b.w};
    ((half4*)(Xh + (size_t)row * D_SZ))[t] = ha;
    ((half4*)(Yh + (size_t)row * D_SZ))[t] = hb;
    float sa = a.x * a.x + a.y * a.y + a.z * a.z + a.w * a.w;
    float sb = b.x * b.x + b.y * b.y + b.z * b.z + b.w * b.w;
    float d0 = a.x - b.x, d1 = a.y - b.y, d2v = a.z - b.z, d3 = a.w - b.w;
    float sd = d0 * d0 + d1 * d1 + d2v * d2v + d3 * d3;
    sa = wave_reduce_add(sa);
    sb = wave_reduce_add(sb);
    sd = wave_reduce_add(sd);
    __shared__ float red[3][4];
    int wave = t >> 6, lane = t & 63;
    if (lane == 0) { red[0][wave] = sa; red[1][wave] = sb; red[2][wave] = sd; }
    __syncthreads();
    if (t == 0) {
        x2[row] = red[0][0] + red[0][1] + red[0][2] + red[0][3];
        y2[row] = red[1][0] + red[1][1] + red[1][2] + red[1][3];
        mth[row] = sqrtf(red[2][0] + red[2][1] + red[2][2] + red[2][3]) + ALPHA;
    }
}

// ---------------------------------------------------------------------------
// gemm_topk: G = Xh @ Yh^T tile (128x128), BK=32 K-loop (proven spill-free,
// conflict-free). XCD-aware block swizzle: 64-block supertiles (8bx x 8by);
// with round-robin block->XCD each XCD's resident set is ~1 B-tile + 8
// A-tiles (~2.3 MB < 4 MB L2), turning staging misses into L2 hits and
// shortening the pre-barrier vmcnt drain (the known structural stall).
// Fused epilogue: d2 tile -> LDS fp16 col-major (Ct[col*132+row]), diag
// pre-clear, packed fp16 selection (waves 0,1 IRR row-pairs; waves 2,3 RII
// full columns). Candidates: 10 fp16 per (row, tile), layout [row][tile][10].
// ---------------------------------------------------------------------------
__global__ void __launch_bounds__(256, 4) gemm_topk_kernel(
    const _Float16* __restrict__ Xh, const _Float16* __restrict__ Yh,
    const float* __restrict__ x2, const float* __restrict__ y2,
    _Float16* __restrict__ CandI, _Float16* __restrict__ CandR) {
    __shared__ _Float16 smem[16896];   // 33792 B: As+Bs (8192 h) | Ct (16896 h)
    _Float16* As = smem;               // 128 x 32 halves
    _Float16* Bs = smem + 4096;
    int tid = threadIdx.x;
    int wave = tid >> 6, lane = tid & 63;
    int waveR = wave >> 1, waveC = wave & 1;
    // XCD-aware swizzle: flat id -> (bx, by) in 8x8 supertiles.
    int id = blockIdx.y * 32 + blockIdx.x;
    int st = id >> 6, w = id & 63;
    int bx = (st & 3) * 8 + (w & 7);
    int by = (st >> 2) * 8 + (w >> 3);
    int q = lane >> 4, mrow = lane & 15;

    floatx4 acc[4][4] = {};

    // Per-thread staging source (swizzled k-slice), invariant over k0.
    int c0 = tid, c1 = 256 + tid;
    int r0 = c0 >> 2, q0 = (c0 & 3) ^ ((r0 >> 1) & 3);
    int r1 = c1 >> 2, q1 = (c1 & 3) ^ ((r1 >> 1) & 3);
    const _Float16* gA0 = Xh + (size_t)(by * 128 + r0) * D_SZ + q0 * 8;
    const _Float16* gB0 = Yh + (size_t)(bx * 128 + r0) * D_SZ + q0 * 8;
    const _Float16* gA1 = Xh + (size_t)(by * 128 + r1) * D_SZ + q1 * 8;
    const _Float16* gB1 = Yh + (size_t)(bx * 128 + r1) * D_SZ + q1 * 8;
    _Float16* la0 = &As[(wave * 64) * 8];
    _Float16* lb0 = &Bs[(wave * 64) * 8];
    _Float16* la1 = &As[(256 + wave * 64) * 8];
    _Float16* lb1 = &Bs[(256 + wave * 64) * 8];

    int aoff[4], boff[4];
#pragma unroll
    for (int mi = 0; mi < 4; ++mi) {
        int R = waveR * 64 + mi * 16 + mrow;
        aoff[mi] = R * 32 + (q ^ ((R >> 1) & 3)) * 8;
    }
#pragma unroll
    for (int ni = 0; ni < 4; ++ni) {
        int R = waveC * 64 + ni * 16 + mrow;
        boff[ni] = R * 32 + (q ^ ((R >> 1) & 3)) * 8;
    }

    for (int k0 = 0; k0 < D_SZ; k0 += 32) {
        __syncthreads();
        __builtin_amdgcn_global_load_lds((gas_t)(const void*)(gA0 + k0), (las_t)(void*)la0, 16, 0, 0);
        __builtin_amdgcn_global_load_lds((gas_t)(const void*)(gB0 + k0), (las_t)(void*)lb0, 16, 0, 0);
        __builtin_amdgcn_global_load_lds((gas_t)(const void*)(gA1 + k0), (las_t)(void*)la1, 16, 0, 0);
        __builtin_amdgcn_global_load_lds((gas_t)(const void*)(gB1 + k0), (las_t)(void*)lb1, 16, 0, 0);
        __syncthreads();
        half8 af[4], bf[4];
#pragma unroll
        for (int mi = 0; mi < 4; ++mi) af[mi] = *(const half8*)&As[aoff[mi]];
#pragma unroll
        for (int ni = 0; ni < 4; ++ni) bf[ni] = *(const half8*)&Bs[boff[ni]];
#pragma unroll
        for (int mi = 0; mi < 4; ++mi)
#pragma unroll
            for (int ni = 0; ni < 4; ++ni)
                acc[mi][ni] = __builtin_amdgcn_mfma_f32_16x16x32_f16(af[mi], bf[ni], acc[mi][ni], 0, 0, 0);
    }
    __syncthreads();  // staging LDS dead; Ct takes over

    // Phase 1: d2 tile -> LDS fp16 col-major: Ct[col*132 + row].
    // C/D layout: col = lane&15, row = q*4 + reg -> 4 consecutive rows = half4.
    _Float16* Ct = smem;
#pragma unroll
    for (int ni = 0; ni < 4; ++ni) {
        int lc = waveC * 64 + ni * 16 + mrow;
        float y2v = y2[bx * 128 + lc];
#pragma unroll
        for (int mi = 0; mi < 4; ++mi) {
            int lr0 = waveR * 64 + mi * 16 + q * 4;
            int gr0 = by * 128 + lr0;
            floatx4 v = acc[mi][ni];
            half4 hv = {(_Float16)(x2[gr0 + 0] + y2v - 2.0f * v[0]),
                        (_Float16)(x2[gr0 + 1] + y2v - 2.0f * v[1]),
                        (_Float16)(x2[gr0 + 2] + y2v - 2.0f * v[2]),
                        (_Float16)(x2[gr0 + 3] + y2v - 2.0f * v[3])};
            *(half4*)&Ct[lc * CT_STRIDE + lr0] = hv;
        }
    }
    __syncthreads();
    // Diagonal pre-clear (removes all per-element diag masking below).
    if (bx == by && tid < 128) Ct[tid * CT_STRIDE + tid] = (_Float16)SENT_F;
    __syncthreads();

    const half2v sent2 = {(_Float16)SENT_F, (_Float16)SENT_F};

    if (wave < 2) {
        // IRR: lane -> row-pair p (rows 2p, 2p+1), col-half chalf.
        int p = wave * 32 + (lane & 31);     // 0..63
        int chalf = lane >> 5;
        half2v b[10];
#pragma unroll
        for (int i = 0; i < 10; ++i) b[i] = sent2;
#pragma unroll 8
        for (int i = 0; i < 64; ++i) {
            int c = chalf * 64 + i;
            half2v v = *(const half2v*)&Ct[c * CT_STRIDE + 2 * p];
            insert10p(b, v);
        }
        // merge the two col-halves (lanes l <-> l^32)
        half2v t[10];
#pragma unroll
        for (int k = 0; k < 10; ++k)
            t[k] = __builtin_bit_cast(half2v, __shfl_xor(__builtin_bit_cast(int, b[k]), 32));
#pragma unroll
        for (int k = 0; k < 10; ++k) insert10p(b, t[k]);
        if (lane < 32) {
            int grow = by * 128 + 2 * p;
            unsigned int* d0 = (unsigned int*)CandI + ((size_t)grow * 32 + bx) * 5;
            unsigned int* d1 = d0 + 32 * 5;  // row grow+1
#pragma unroll
            for (int k = 0; k < 5; ++k) {
                unsigned int u0 = __builtin_bit_cast(unsigned int, b[2 * k]);
                unsigned int u1 = __builtin_bit_cast(unsigned int, b[2 * k + 1]);
                d0[k] = (u0 & 0xFFFFu) | (u1 << 16);            // low halves = row 2p
                d1[k] = (u0 >> 16) | (u1 & 0xFFFF0000u);        // high halves = row 2p+1
            }
        }
    } else {
        // RII: lane -> full column c; packed halves = even/odd row sub-streams.
        int c = (wave - 2) * 64 + lane;      // 0..127
        half2v b[10];
#pragma unroll
        for (int i = 0; i < 10; ++i) b[i] = sent2;
        const half2v* colp = (const half2v*)&Ct[c * CT_STRIDE];
#pragma unroll 8
        for (int i = 0; i < 64; ++i) insert10p(b, colp[i]);
        // merge even/odd streams: insert the 16-bit-rotated lists (snapshot first)
        half2v sw[10];
#pragma unroll
        for (int k = 0; k < 10; ++k) {
            unsigned int u = __builtin_bit_cast(unsigned int, b[k]);
            sw[k] = __builtin_bit_cast(half2v, (u >> 16) | (u << 16));
        }
#pragma unroll
        for (int k = 0; k < 10; ++k) insert10p(b, sw[k]);
        // low halves of b[0..9] = column top-10
        int gcol = bx * 128 + c;
        unsigned int* d = (unsigned int*)CandR + ((size_t)gcol * 32 + by) * 5;
#pragma unroll
        for (int k = 0; k < 5; ++k) {
            unsigned int u0 = __builtin_bit_cast(unsigned int, b[2 * k]);
            unsigned int u1 = __builtin_bit_cast(unsigned int, b[2 * k + 1]);
            d[k] = (u0 & 0xFFFFu) | (u1 << 16);
        }
    }
}

// ---------------------------------------------------------------------------
// merge: 2048 blocks, ONE row per wave (max TLP; the 10-round reduce is a
// serial latency chain). NO atomics — per-row partials to Srow/Zrow (R9's
// 4096 same-address atomicAdds serialized at ~33 cyc each = 57.9 us).
// ---------------------------------------------------------------------------
__global__ void __launch_bounds__(256) merge_kernel(
    const _Float16* __restrict__ CandI, const _Float16* __restrict__ CandR,
    const float* __restrict__ mth,
    float* __restrict__ Srow, float* __restrict__ Zrow) {
    int wave = threadIdx.x >> 6, lane = threadIdx.x & 63;
    int r = blockIdx.x * 4 + wave;              // 0..8191
    int row = r & (B_SZ - 1);
    const _Float16* cp = ((r < B_SZ) ? CandI : CandR) + (size_t)row * 320;
    float best[10];
#pragma unroll
    for (int i = 0; i < 10; ++i) best[i] = BIGF;
#pragma unroll
    for (int j = 0; j < 5; ++j) insert10(best, (float)cp[j * 64 + lane]);

    float mrow = mth[row];
    float s = 0.f, z = 0.f;
#pragma unroll
    for (int round = 0; round < 10; ++round) {
        float v0 = best[0];
        float g = v0;
#pragma unroll
        for (int off = 32; off; off >>= 1) g = fminf(g, __shfl_xor(g, off));
        unsigned long long ball = __ballot(v0 == g);
        int leader = __ffsll(ball) - 1;
        if (lane == leader) {
#pragma unroll
            for (int p = 0; p < 9; ++p) best[p] = best[p + 1];
            best[9] = BIGF;
        }
        float d = sqrtf(fmaxf(g, 0.f));
        float c = fmaxf(mrow - d, 0.f);
        s += c;
        z += (c == 0.f) ? 1.f : 0.f;
    }
    if (lane == 0) { Srow[r] = s; Zrow[r] = z; }
}

// ---------------------------------------------------------------------------
// finalize: reduce per-row partials -> [loss_irr, loss_rii, bad_irr, bad_rii]
// Srow/Zrow are 8192 floats each = 2048 float4: [0,1024) IRR, [1024,2048) RII.
// ---------------------------------------------------------------------------
__global__ void __launch_bounds__(256) finalize_kernel(
    const float* __restrict__ Srow, const float* __restrict__ Zrow,
    float* __restrict__ out) {
    __shared__ float red[256][4];
    int t = threadIdx.x;
    float s0 = 0, s1 = 0, z0 = 0, z1 = 0;
#pragma unroll
    for (int k = 0; k < 8; ++k) {
        int i = k * 256 + t;
        float4 sv = ((const float4*)Srow)[i];
        float4 zv = ((const float4*)Zrow)[i];
        float ss = sv.x + sv.y + sv.z + sv.w;
        float zz = zv.x + zv.y + zv.z + zv.w;
        if (i < 1024) { s0 += ss; z0 += zz; } else { s1 += ss; z1 += zz; }
    }
    red[t][0] = s0; red[t][1] = s1; red[t][2] = z0; red[t][3] = z1;
    __syncthreads();
    for (int off = 128; off > 0; off >>= 1) {
        if (t < off) {
#pragma unroll
            for (int j = 0; j < 4; ++j) red[t][j] += red[t + off][j];
        }
        __syncthreads();
    }
    if (t == 0) {
        const float inv = 1.0f / (float)(B_SZ * 10);
        out[0] = red[0][0] * inv;  // loss_irr
        out[1] = red[0][1] * inv;  // loss_rii
        out[2] = red[0][2] * inv;  // bad_irr
        out[3] = red[0][3] * inv;  // bad_rii
    }
}

// ---------------------------------------------------------------------------
extern "C" void kernel_launch(void* const* d_in, const int* in_sizes, int n_in,
                              void* d_out, int out_size, void* d_ws, size_t ws_size,
                              hipStream_t stream) {
    const float* in1 = (const float*)d_in[0];
    const float* in2 = (const float*)d_in[1];
    float* out = (float*)d_out;

    char* ws = (char*)d_ws;
    const size_t MB = 1024 * 1024;
    _Float16* Xh = (_Float16*)(ws);                  // 8 MiB
    _Float16* Yh = (_Float16*)(ws + 8 * MB);         // 8 MiB
    _Float16* CandI = (_Float16*)(ws + 16 * MB);     // 4096*32*10*2B = 2.62 MB
    _Float16* CandR = (_Float16*)(ws + 19 * MB);     // 2.62 MB
    float* x2   = (float*)(ws + 22 * MB);
    float* y2   = x2 + B_SZ;
    float* mth  = y2 + B_SZ;
    float* Srow = mth + B_SZ;                        // 8192 floats
    float* Zrow = Srow + 2 * B_SZ;                   // 8192 floats
    const size_t needed = 22 * MB + (size_t)(3 * B_SZ + 4 * B_SZ) * sizeof(float);
    if (ws_size < needed) return;

    hipLaunchKernelGGL(prep_kernel, dim3(B_SZ), dim3(256), 0, stream,
                       in1, in2, Xh, Yh, x2, y2, mth);
    hipLaunchKernelGGL(gemm_topk_kernel, dim3(32, 32), dim3(256), 0, stream,
                       Xh, Yh, x2, y2, CandI, CandR);
    hipLaunchKernelGGL(merge_kernel, dim3(2048), dim3(256), 0, stream,
                       CandI, CandR, mth, Srow, Zrow);
    hipLaunchKernelGGL(finalize_kernel, dim3(1), dim3(256), 0, stream,
                       Srow, Zrow, out);
}

// Round 12
// 132.607 us; speedup vs baseline: 1.4432x; 1.0882x over previous
//
#include <hip/hip_runtime.h>
#include <hip/hip_fp16.h>

#define ALPHA 0.3f
#define B_SZ 4096
#define D_SZ 1024
#define CT_STRIDE 132   // multiple of 4: aligned half4 stores, 2-way banks on scans
#define BIGF 3.0e38f
#define SENT_F 60000.0f // fp16-representable sentinel >> any d2 (~4100 max)

typedef __attribute__((ext_vector_type(4))) _Float16 half4;
typedef __attribute__((ext_vector_type(2))) _Float16 half2v;
typedef __attribute__((ext_vector_type(4))) float floatx4;

typedef __attribute__((address_space(1))) const void* gas_t;
typedef __attribute__((address_space(3))) void* las_t;

__device__ __forceinline__ float wave_reduce_add(float v) {
#pragma unroll
    for (int off = 32; off; off >>= 1) v += __shfl_xor(v, off);
    return v;
}

// sorted ascending insert of x into best[0..9] (branchless, scalar f32)
__device__ __forceinline__ void insert10(float (&best)[10], float x) {
#pragma unroll
    for (int p = 0; p < 10; ++p) {
        float lo = fminf(best[p], x);
        x = fmaxf(best[p], x);
        best[p] = lo;
    }
}

// packed: two independent sorted-10 lists; lowers to v_pk_min/max_f16
__device__ __forceinline__ void insert10p(half2v (&b)[10], half2v x) {
#pragma unroll
    for (int p = 0; p < 10; ++p) {
        half2v lo = __builtin_elementwise_min(b[p], x);
        x = __builtin_elementwise_max(b[p], x);
        b[p] = lo;
    }
}

// ---------------------------------------------------------------------------
// prep: fp32 -> fp8 e4m3 convert (packed cvt builtin), EXACT fp32 row norms
// x2/y2 and threshold m[i] (quantization only enters through the Gram term).
// ---------------------------------------------------------------------------
__global__ void __launch_bounds__(256) prep_kernel(
    const float* __restrict__ in1, const float* __restrict__ in2,
    unsigned char* __restrict__ Xq, unsigned char* __restrict__ Yq,
    float* __restrict__ x2, float* __restrict__ y2, float* __restrict__ mth) {
    int row = blockIdx.x;
    int t = threadIdx.x;
    const float4* a4 = (const float4*)(in1 + (size_t)row * D_SZ);
    const float4* b4 = (const float4*)(in2 + (size_t)row * D_SZ);
    float4 a = a4[t], b = b4[t];
    int ua = 0, ub = 0;
    ua = __builtin_amdgcn_cvt_pk_fp8_f32(a.x, a.y, ua, false);
    ua = __builtin_amdgcn_cvt_pk_fp8_f32(a.z, a.w, ua, true);
    ub = __builtin_amdgcn_cvt_pk_fp8_f32(b.x, b.y, ub, false);
    ub = __builtin_amdgcn_cvt_pk_fp8_f32(b.z, b.w, ub, true);
    ((int*)(Xq + (size_t)row * D_SZ))[t] = ua;
    ((int*)(Yq + (size_t)row * D_SZ))[t] = ub;
    float sa = a.x * a.x + a.y * a.y + a.z * a.z + a.w * a.w;
    float sb = b.x * b.x + b.y * b.y + b.z * b.z + b.w * b.w;
    float d0 = a.x - b.x, d1 = a.y - b.y, d2v = a.z - b.z, d3 = a.w - b.w;
    float sd = d0 * d0 + d1 * d1 + d2v * d2v + d3 * d3;
    sa = wave_reduce_add(sa);
    sb = wave_reduce_add(sb);
    sd = wave_reduce_add(sd);
    __shared__ float red[3][4];
    int wave = t >> 6, lane = t & 63;
    if (lane == 0) { red[0][wave] = sa; red[1][wave] = sb; red[2][wave] = sd; }
    __syncthreads();
    if (t == 0) {
        x2[row] = red[0][0] + red[0][1] + red[0][2] + red[0][3];
        y2[row] = red[1][0] + red[1][1] + red[1][2] + red[1][3];
        mth[row] = sqrtf(red[2][0] + red[2][1] + red[2][2] + red[2][3]) + ALPHA;
    }
}

// ---------------------------------------------------------------------------
// gemm_topk (fp8 e4m3): G = Xq @ Yq^T tile (128x128), BK=64 — 16 K-iters,
// HALF the barriers of the f16 BK=32 version (the barrier drain is the
// measured bottleneck), with fp8 frags (2 VGPR) keeping registers at the
// R4-proven level (no R5-style spill). Staging rows are 64 B; 16B-unit XOR
// swizzle u' = u ^ ((r>>1)&3) keeps ds_read_b64 fragment reads ~2-way.
// mfma_f32_16x16x32_fp8_fp8, 2 k-steps per iteration.
// Fused epilogue identical to R11: Ct fp16 col-major, diag pre-clear,
// packed-fp16 wave-specialized top-10 (waves 0,1 IRR; waves 2,3 RII).
// ---------------------------------------------------------------------------
__global__ void __launch_bounds__(256) gemm_topk_kernel(
    const unsigned char* __restrict__ Xq, const unsigned char* __restrict__ Yq,
    const float* __restrict__ x2, const float* __restrict__ y2,
    _Float16* __restrict__ CandI, _Float16* __restrict__ CandR) {
    __shared__ __align__(16) unsigned char smem[33792]; // As+Bs 16 KB | Ct 33792 B
    unsigned char* As = smem;          // 128 rows x 64 B
    unsigned char* Bs = smem + 8192;
    int tid = threadIdx.x;
    int wave = tid >> 6, lane = tid & 63;
    int waveR = wave >> 1, waveC = wave & 1;
    // XCD-aware supertile swizzle (measured neutral, kept from R11).
    int id = blockIdx.y * 32 + blockIdx.x;
    int st = id >> 6, w = id & 63;
    int bx = (st & 3) * 8 + (w & 7);
    int by = (st >> 2) * 8 + (w >> 3);
    int q = lane >> 4, mrow = lane & 15;

    floatx4 acc[4][4] = {};

    // Staging: per tile 512 16B-cells per iter; cell c: r=c>>2, u=c&3,
    // source unit g = u ^ ((r>>1)&3). Two instructions per tile per thread.
    const unsigned char* srcA[2];
    const unsigned char* srcB[2];
    unsigned char* dstA[2];
    unsigned char* dstB[2];
#pragma unroll
    for (int i = 0; i < 2; ++i) {
        int c = i * 256 + tid;
        int r = c >> 2, u = c & 3;
        int g = u ^ ((r >> 1) & 3);
        srcA[i] = Xq + (size_t)(by * 128 + r) * D_SZ + g * 16;
        srcB[i] = Yq + (size_t)(bx * 128 + r) * D_SZ + g * 16;
        dstA[i] = As + (i * 256 + wave * 64) * 16;
        dstB[i] = Bs + (i * 256 + wave * 64) * 16;
    }

    // Reader byte-offsets: row R, k-step ks, slice q -> unit ks*2+(q>>1),
    // swizzled by (R>>1)&3, + (q&1)*8 within unit. 8B-aligned ds_read_b64.
    int aoff[2][4], boff[2][4];
#pragma unroll
    for (int mi = 0; mi < 4; ++mi) {
        int Ra = waveR * 64 + mi * 16 + mrow;
        int Rb = waveC * 64 + mi * 16 + mrow;
#pragma unroll
        for (int ks = 0; ks < 2; ++ks) {
            int u = ks * 2 + (q >> 1);
            aoff[ks][mi] = Ra * 64 + (u ^ ((Ra >> 1) & 3)) * 16 + (q & 1) * 8;
            boff[ks][mi] = Rb * 64 + (u ^ ((Rb >> 1) & 3)) * 16 + (q & 1) * 8;
        }
    }

    for (int k0 = 0; k0 < D_SZ; k0 += 64) {
        __syncthreads();
        __builtin_amdgcn_global_load_lds((gas_t)(const void*)(srcA[0] + k0), (las_t)(void*)dstA[0], 16, 0, 0);
        __builtin_amdgcn_global_load_lds((gas_t)(const void*)(srcB[0] + k0), (las_t)(void*)dstB[0], 16, 0, 0);
        __builtin_amdgcn_global_load_lds((gas_t)(const void*)(srcA[1] + k0), (las_t)(void*)dstA[1], 16, 0, 0);
        __builtin_amdgcn_global_load_lds((gas_t)(const void*)(srcB[1] + k0), (las_t)(void*)dstB[1], 16, 0, 0);
        __syncthreads();
#pragma unroll
        for (int ks = 0; ks < 2; ++ks) {
            long af[4], bf[4];
#pragma unroll
            for (int mi = 0; mi < 4; ++mi) af[mi] = *(const long*)&As[aoff[ks][mi]];
#pragma unroll
            for (int ni = 0; ni < 4; ++ni) bf[ni] = *(const long*)&Bs[boff[ks][ni]];
#pragma unroll
            for (int mi = 0; mi < 4; ++mi)
#pragma unroll
                for (int ni = 0; ni < 4; ++ni)
                    acc[mi][ni] = __builtin_amdgcn_mfma_f32_16x16x32_fp8_fp8(af[mi], bf[ni], acc[mi][ni], 0, 0, 0);
        }
    }
    __syncthreads();  // staging LDS dead; Ct takes over

    // Phase 1: d2 tile -> LDS fp16 col-major: Ct[col*132 + row].
    // C/D layout: col = lane&15, row = q*4 + reg -> 4 consecutive rows = half4.
    _Float16* Ct = (_Float16*)smem;
#pragma unroll
    for (int ni = 0; ni < 4; ++ni) {
        int lc = waveC * 64 + ni * 16 + mrow;
        float y2v = y2[bx * 128 + lc];
#pragma unroll
        for (int mi = 0; mi < 4; ++mi) {
            int lr0 = waveR * 64 + mi * 16 + q * 4;
            int gr0 = by * 128 + lr0;
            floatx4 v = acc[mi][ni];
            half4 hv = {(_Float16)(x2[gr0 + 0] + y2v - 2.0f * v[0]),
                        (_Float16)(x2[gr0 + 1] + y2v - 2.0f * v[1]),
                        (_Float16)(x2[gr0 + 2] + y2v - 2.0f * v[2]),
                        (_Float16)(x2[gr0 + 3] + y2v - 2.0f * v[3])};
            *(half4*)&Ct[lc * CT_STRIDE + lr0] = hv;
        }
    }
    __syncthreads();
    // Diagonal pre-clear (removes all per-element diag masking below).
    if (bx == by && tid < 128) Ct[tid * CT_STRIDE + tid] = (_Float16)SENT_F;
    __syncthreads();

    const half2v sent2 = {(_Float16)SENT_F, (_Float16)SENT_F};

    if (wave < 2) {
        // IRR: lane -> row-pair p (rows 2p, 2p+1), col-half chalf.
        int p = wave * 32 + (lane & 31);     // 0..63
        int chalf = lane >> 5;
        half2v b[10];
#pragma unroll
        for (int i = 0; i < 10; ++i) b[i] = sent2;
#pragma unroll 8
        for (int i = 0; i < 64; ++i) {
            int c = chalf * 64 + i;
            half2v v = *(const half2v*)&Ct[c * CT_STRIDE + 2 * p];
            insert10p(b, v);
        }
        // merge the two col-halves (lanes l <-> l^32)
        half2v t[10];
#pragma unroll
        for (int k = 0; k < 10; ++k)
            t[k] = __builtin_bit_cast(half2v, __shfl_xor(__builtin_bit_cast(int, b[k]), 32));
#pragma unroll
        for (int k = 0; k < 10; ++k) insert10p(b, t[k]);
        if (lane < 32) {
            int grow = by * 128 + 2 * p;
            unsigned int* d0 = (unsigned int*)CandI + ((size_t)grow * 32 + bx) * 5;
            unsigned int* d1 = d0 + 32 * 5;  // row grow+1
#pragma unroll
            for (int k = 0; k < 5; ++k) {
                unsigned int u0 = __builtin_bit_cast(unsigned int, b[2 * k]);
                unsigned int u1 = __builtin_bit_cast(unsigned int, b[2 * k + 1]);
                d0[k] = (u0 & 0xFFFFu) | (u1 << 16);            // low halves = row 2p
                d1[k] = (u0 >> 16) | (u1 & 0xFFFF0000u);        // high halves = row 2p+1
            }
        }
    } else {
        // RII: lane -> full column c; packed halves = even/odd row sub-streams.
        int c = (wave - 2) * 64 + lane;      // 0..127
        half2v b[10];
#pragma unroll
        for (int i = 0; i < 10; ++i) b[i] = sent2;
        const half2v* colp = (const half2v*)&Ct[c * CT_STRIDE];
#pragma unroll 8
        for (int i = 0; i < 64; ++i) insert10p(b, colp[i]);
        // merge even/odd streams: insert the 16-bit-rotated lists (snapshot first)
        half2v sw[10];
#pragma unroll
        for (int k = 0; k < 10; ++k) {
            unsigned int u = __builtin_bit_cast(unsigned int, b[k]);
            sw[k] = __builtin_bit_cast(half2v, (u >> 16) | (u << 16));
        }
#pragma unroll
        for (int k = 0; k < 10; ++k) insert10p(b, sw[k]);
        // low halves of b[0..9] = column top-10
        int gcol = bx * 128 + c;
        unsigned int* d = (unsigned int*)CandR + ((size_t)gcol * 32 + by) * 5;
#pragma unroll
        for (int k = 0; k < 5; ++k) {
            unsigned int u0 = __builtin_bit_cast(unsigned int, b[2 * k]);
            unsigned int u1 = __builtin_bit_cast(unsigned int, b[2 * k + 1]);
            d[k] = (u0 & 0xFFFFu) | (u1 << 16);
        }
    }
}

// ---------------------------------------------------------------------------
// merge: 2048 blocks, ONE row per wave (max TLP; the 10-round reduce is a
// serial latency chain). NO atomics — per-row partials to Srow/Zrow.
// ---------------------------------------------------------------------------
__global__ void __launch_bounds__(256) merge_kernel(
    const _Float16* __restrict__ CandI, const _Float16* __restrict__ CandR,
    const float* __restrict__ mth,
    float* __restrict__ Srow, float* __restrict__ Zrow) {
    int wave = threadIdx.x >> 6, lane = threadIdx.x & 63;
    int r = blockIdx.x * 4 + wave;              // 0..8191
    int row = r & (B_SZ - 1);
    const _Float16* cp = ((r < B_SZ) ? CandI : CandR) + (size_t)row * 320;
    float best[10];
#pragma unroll
    for (int i = 0; i < 10; ++i) best[i] = BIGF;
#pragma unroll
    for (int j = 0; j < 5; ++j) insert10(best, (float)cp[j * 64 + lane]);

    float mrow = mth[row];
    float s = 0.f, z = 0.f;
#pragma unroll
    for (int round = 0; round < 10; ++round) {
        float v0 = best[0];
        float g = v0;
#pragma unroll
        for (int off = 32; off; off >>= 1) g = fminf(g, __shfl_xor(g, off));
        unsigned long long ball = __ballot(v0 == g);
        int leader = __ffsll(ball) - 1;
        if (lane == leader) {
#pragma unroll
            for (int p = 0; p < 9; ++p) best[p] = best[p + 1];
            best[9] = BIGF;
        }
        float d = sqrtf(fmaxf(g, 0.f));
        float c = fmaxf(mrow - d, 0.f);
        s += c;
        z += (c == 0.f) ? 1.f : 0.f;
    }
    if (lane == 0) { Srow[r] = s; Zrow[r] = z; }
}

// ---------------------------------------------------------------------------
// finalize: reduce per-row partials -> [loss_irr, loss_rii, bad_irr, bad_rii]
// Srow/Zrow are 8192 floats each = 2048 float4: [0,1024) IRR, [1024,2048) RII.
// ---------------------------------------------------------------------------
__global__ void __launch_bounds__(256) finalize_kernel(
    const float* __restrict__ Srow, const float* __restrict__ Zrow,
    float* __restrict__ out) {
    __shared__ float red[256][4];
    int t = threadIdx.x;
    float s0 = 0, s1 = 0, z0 = 0, z1 = 0;
#pragma unroll
    for (int k = 0; k < 8; ++k) {
        int i = k * 256 + t;
        float4 sv = ((const float4*)Srow)[i];
        float4 zv = ((const float4*)Zrow)[i];
        float ss = sv.x + sv.y + sv.z + sv.w;
        float zz = zv.x + zv.y + zv.z + zv.w;
        if (i < 1024) { s0 += ss; z0 += zz; } else { s1 += ss; z1 += zz; }
    }
    red[t][0] = s0; red[t][1] = s1; red[t][2] = z0; red[t][3] = z1;
    __syncthreads();
    for (int off = 128; off > 0; off >>= 1) {
        if (t < off) {
#pragma unroll
            for (int j = 0; j < 4; ++j) red[t][j] += red[t + off][j];
        }
        __syncthreads();
    }
    if (t == 0) {
        const float inv = 1.0f / (float)(B_SZ * 10);
        out[0] = red[0][0] * inv;  // loss_irr
        out[1] = red[0][1] * inv;  // loss_rii
        out[2] = red[0][2] * inv;  // bad_irr
        out[3] = red[0][3] * inv;  // bad_rii
    }
}

// ---------------------------------------------------------------------------
extern "C" void kernel_launch(void* const* d_in, const int* in_sizes, int n_in,
                              void* d_out, int out_size, void* d_ws, size_t ws_size,
                              hipStream_t stream) {
    const float* in1 = (const float*)d_in[0];
    const float* in2 = (const float*)d_in[1];
    float* out = (float*)d_out;

    char* ws = (char*)d_ws;
    const size_t MB = 1024 * 1024;
    unsigned char* Xq = (unsigned char*)(ws);        // 4 MiB
    unsigned char* Yq = (unsigned char*)(ws + 4 * MB);  // 4 MiB
    _Float16* CandI = (_Float16*)(ws + 8 * MB);      // 4096*32*10*2B = 2.62 MB
    _Float16* CandR = (_Float16*)(ws + 11 * MB);     // 2.62 MB
    float* x2   = (float*)(ws + 14 * MB);
    float* y2   = x2 + B_SZ;
    float* mth  = y2 + B_SZ;
    float* Srow = mth + B_SZ;                        // 8192 floats
    float* Zrow = Srow + 2 * B_SZ;                   // 8192 floats
    const size_t needed = 14 * MB + (size_t)(3 * B_SZ + 4 * B_SZ) * sizeof(float);
    if (ws_size < needed) return;

    hipLaunchKernelGGL(prep_kernel, dim3(B_SZ), dim3(256), 0, stream,
                       in1, in2, Xq, Yq, x2, y2, mth);
    hipLaunchKernelGGL(gemm_topk_kernel, dim3(32, 32), dim3(256), 0, stream,
                       Xq, Yq, x2, y2, CandI, CandR);
    hipLaunchKernelGGL(merge_kernel, dim3(2048), dim3(256), 0, stream,
                       CandI, CandR, mth, Srow, Zrow);
    hipLaunchKernelGGL(finalize_kernel, dim3(1), dim3(256), 0, stream,
                       Srow, Zrow, out);
}